// Round 1
// baseline (3692.113 us; speedup 1.0000x reference)
//
#include <hip/hip_runtime.h>
#include <stdint.h>

typedef _Float16 f16;
typedef _Float16 half8 __attribute__((ext_vector_type(8)));
typedef float f32x4 __attribute__((ext_vector_type(4)));

// ---------------------------------------------------------------------------
// MoE constants (fixed by the problem)
//   B=8, T=2048, C=1024, H=4C=4096, E=8, K=2, CAP=320
//   tokens M = 16384, expert slots = E*B*CAP = 20480, rows/expert = 2560
// ---------------------------------------------------------------------------

__device__ __forceinline__ void gload16(const void* g, void* l) {
  __builtin_amdgcn_global_load_lds(
      (const __attribute__((address_space(1))) void*)g,
      (__attribute__((address_space(3))) void*)l, 16, 0, 0);
}

// ---------------------------------------------------------------------------
// 128x128-tile f16 MFMA GEMM (m97 structure). C = A @ B^T_stored + bias.
//  A: [M][lda] f16 row-major. B stored N-major: [N][ldb] f16 (ldb == K).
//  SPLIT3: A=A0+2^-12*A1, B=B0+2^-12*B1 (lo parts pre-scaled x4096);
//          3 K-passes: lo*hi, hi*lo, (scale acc 2^-12), hi*hi  -> ~fp32 exact.
//  EPI: 0 = relu + split-write (hi,lo*4096) f16   (router h1)
//       1 = relu + f32 write                       (router h2)
//       2 = relu + f16 write                       (expert h)
//       3 = +bias, gated scatter atomicAdd to out  (expert y -> tokens)
// ---------------------------------------------------------------------------
template<int EPI, bool SPLIT3>
__launch_bounds__(256)
__global__ void gemm128(const f16* __restrict__ A0, const f16* __restrict__ A1,
                        const f16* __restrict__ B0, const f16* __restrict__ B1,
                        int N, int Kd, int lda, int ldb,
                        const float* __restrict__ bias, int bias_stride, int rows_per_exp,
                        float* __restrict__ oF, f16* __restrict__ oH, f16* __restrict__ oHlo,
                        int ldo,
                        const int* __restrict__ cnt, const int* __restrict__ idxl,
                        const float* __restrict__ gatel, float* __restrict__ oScat)
{
  __shared__ f16 sA[128 * 64];
  __shared__ f16 sB[128 * 64];
  const int tid  = threadIdx.x;
  const int lane = tid & 63, wv = tid >> 6;
  const int wm = wv >> 1, wn = wv & 1;
  const int m0 = blockIdx.y * 128, n0 = blockIdx.x * 128;

  int e = 0;
  if (rows_per_exp > 0) e = m0 / rows_per_exp;
  const f16* Bh = B0 + (size_t)e * N * ldb;   // expert weight block (e==0 for router)
  const f16* Bl = B1;

  f32x4 acc[4][4] = {};

  const int nk  = Kd >> 6;                    // K-steps of 64
  const int NIT = SPLIT3 ? 3 * nk : nk;
  const int sm = lane >> 3;                   // staging: row within 8-row chunk
  const int sk = (lane & 7) << 3;             // staging: k offset (8 f16 = 16B)

  int kin = 0, pass = 0;
  for (int it = 0; it < NIT; ++it) {
    const f16* Ab; const f16* Bb;
    if (SPLIT3) {
      if (it == 2 * nk) {                     // lo-passes done: scale by 2^-12
        #pragma unroll
        for (int mi = 0; mi < 4; ++mi)
          #pragma unroll
          for (int ni = 0; ni < 4; ++ni)
            acc[mi][ni] = acc[mi][ni] * 2.44140625e-4f;
      }
      Ab = (pass == 0) ? A1 : A0;
      Bb = (pass == 1) ? Bl : Bh;
    } else { Ab = A0; Bb = Bh; }
    const int kk = kin << 6;

    #pragma unroll
    for (int i = 0; i < 4; ++i) {             // stage A,B tiles: 8 gload/wave
      const int ch = wv * 4 + i;
      const int rr = ch * 8 + sm;
      gload16(Ab + (size_t)(m0 + rr) * lda + kk + sk, (void*)&sA[ch * 512]);
      gload16(Bb + (size_t)(n0 + rr) * ldb + kk + sk, (void*)&sB[ch * 512]);
    }
    __syncthreads();

    #pragma unroll
    for (int kc = 0; kc < 2; ++kc) {
      const int ko = kc * 32 + (lane >> 4) * 8;
      half8 aF[4], bF[4];
      #pragma unroll
      for (int mi = 0; mi < 4; ++mi)
        aF[mi] = *(const half8*)&sA[(wm * 64 + mi * 16 + (lane & 15)) * 64 + ko];
      #pragma unroll
      for (int ni = 0; ni < 4; ++ni)
        bF[ni] = *(const half8*)&sB[(wn * 64 + ni * 16 + (lane & 15)) * 64 + ko];
      #pragma unroll
      for (int mi = 0; mi < 4; ++mi)
        #pragma unroll
        for (int ni = 0; ni < 4; ++ni)
          acc[mi][ni] = __builtin_amdgcn_mfma_f32_16x16x32_f16(aF[mi], bF[ni], acc[mi][ni], 0, 0, 0);
    }
    __syncthreads();
    if (++kin == nk) { kin = 0; ++pass; }
  }

  // epilogue ---------------------------------------------------------------
  float bv[4];
  #pragma unroll
  for (int ni = 0; ni < 4; ++ni) {
    const int col = n0 + wn * 64 + ni * 16 + (lane & 15);
    bv[ni] = bias[(size_t)e * bias_stride + col];
  }
  #pragma unroll
  for (int mi = 0; mi < 4; ++mi) {
    #pragma unroll
    for (int r = 0; r < 4; ++r) {
      const int row = m0 + wm * 64 + mi * 16 + (lane >> 4) * 4 + r;
      if (EPI == 3) {
        const int tr = row - e * rows_per_exp;      // slot within expert
        const int bb = tr / 320, s = tr - bb * 320; // batch row, capacity slot
        const int pr = e * 8 + bb;
        if (s < cnt[pr]) {
          const int   t = idxl[pr * 320 + s];
          const float g = gatel[pr * 320 + s];
          float* orow = oScat + ((size_t)bb * 2048 + t) * 1024;
          #pragma unroll
          for (int ni = 0; ni < 4; ++ni) {
            const int col = n0 + wn * 64 + ni * 16 + (lane & 15);
            atomicAdd(&orow[col], g * (acc[mi][ni][r] + bv[ni]));
          }
        }
      } else {
        #pragma unroll
        for (int ni = 0; ni < 4; ++ni) {
          const int col = n0 + wn * 64 + ni * 16 + (lane & 15);
          float v = acc[mi][ni][r] + bv[ni];
          v = fmaxf(v, 0.0f);
          const size_t o = (size_t)row * ldo + col;
          if (EPI == 0) {
            const f16 h = (f16)v;
            oH[o]   = h;
            oHlo[o] = (f16)((v - (float)h) * 4096.0f);
          } else if (EPI == 1) {
            oF[o] = v;
          } else {
            oH[o] = (f16)v;
          }
        }
      }
    }
  }
}

// ---------------------------------------------------------------------------
// x (f32) -> hi f16 + lo f16 (x4096), 8 elems/thread
// ---------------------------------------------------------------------------
__global__ void split_x(const float* __restrict__ x, f16* __restrict__ hi,
                        f16* __restrict__ lo, int n)
{
  const int i = blockIdx.x * 256 + threadIdx.x;
  if (i * 8 >= n) return;
  const f32x4 a = ((const f32x4*)x)[2 * i];
  const f32x4 b = ((const f32x4*)x)[2 * i + 1];
  half8 h, l;
  #pragma unroll
  for (int j = 0; j < 4; ++j) {
    float v = a[j]; f16 hh = (f16)v;
    h[j] = hh; l[j] = (f16)((v - (float)hh) * 4096.0f);
    v = b[j]; hh = (f16)v;
    h[4 + j] = hh; l[4 + j] = (f16)((v - (float)hh) * 4096.0f);
  }
  ((half8*)hi)[i] = h;
  ((half8*)lo)[i] = l;
}

// ---------------------------------------------------------------------------
// Transpose-convert: in f32 [R][Cc] -> out f16 [Cc][R] (optional split lo)
// blockIdx.z batches experts.
// ---------------------------------------------------------------------------
template<bool SPLIT>
__global__ void transpose_conv(const float* __restrict__ in, f16* __restrict__ oh,
                               f16* __restrict__ ol, int R, int Cc)
{
  __shared__ float tile[64][65];
  const size_t boff = (size_t)blockIdx.z * R * Cc;
  in += boff; oh += boff;
  if (SPLIT) ol += boff;
  const int c0 = blockIdx.x * 64, r0 = blockIdx.y * 64;
  #pragma unroll
  for (int i = 0; i < 16; ++i) {
    const int idx = i * 256 + threadIdx.x;
    const int r = idx >> 6, c = idx & 63;
    tile[r][c] = in[(size_t)(r0 + r) * Cc + (c0 + c)];
  }
  __syncthreads();
  #pragma unroll
  for (int i = 0; i < 16; ++i) {
    const int idx = i * 256 + threadIdx.x;
    const int ro = idx >> 6, co = idx & 63;
    const float v = tile[co][ro];
    const f16 h = (f16)v;
    const size_t o = (size_t)(c0 + ro) * R + (r0 + co);
    oh[o] = h;
    if (SPLIT) ol[o] = (f16)((v - (float)h) * 4096.0f);
  }
}

// ---------------------------------------------------------------------------
// logits (f64-accurate dot with rw3) + softmax f32 + stable top-2
// one block per token; h2 is the current 4096-token chunk (f32)
// ---------------------------------------------------------------------------
__global__ void logits_topk(const float* __restrict__ h2, const float* __restrict__ w3,
                            const float* __restrict__ b3, int tok0,
                            int* __restrict__ eidx, float* __restrict__ gval)
{
  const int t = blockIdx.x;
  const float* hrow = h2 + (size_t)t * 4096;
  double p[8];
  #pragma unroll
  for (int e = 0; e < 8; ++e) p[e] = 0.0;
  for (int i = 0; i < 16; ++i) {
    const int k = i * 256 + threadIdx.x;
    const float h = hrow[k];
    const float* w = w3 + (size_t)k * 8;
    #pragma unroll
    for (int e = 0; e < 8; ++e) p[e] += (double)h * (double)w[e];
  }
  #pragma unroll
  for (int e = 0; e < 8; ++e)
    for (int off = 32; off > 0; off >>= 1)
      p[e] += __shfl_down(p[e], off);
  __shared__ double sp[4][8];
  const int lane = threadIdx.x & 63, wv = threadIdx.x >> 6;
  if (lane == 0) {
    #pragma unroll
    for (int e = 0; e < 8; ++e) sp[wv][e] = p[e];
  }
  __syncthreads();
  if (threadIdx.x == 0) {
    float l[8];
    #pragma unroll
    for (int e = 0; e < 8; ++e)
      l[e] = (float)(sp[0][e] + sp[1][e] + sp[2][e] + sp[3][e] + (double)b3[e]);
    float mx = l[0];
    for (int e = 1; e < 8; ++e) mx = fmaxf(mx, l[e]);
    float ex[8], s = 0.f;
    for (int e = 0; e < 8; ++e) { ex[e] = expf(l[e] - mx); s += ex[e]; }
    float p1 = -1.f, p2 = -1.f; int e1 = 0, e2 = 0;
    for (int e = 0; e < 8; ++e) {             // strict '>' = lax.top_k stable tie-break
      const float pe = ex[e] / s;
      if (pe > p1)      { p2 = p1; e2 = e1; p1 = pe; e1 = e; }
      else if (pe > p2) { p2 = pe; e2 = e; }
    }
    const int tg = tok0 + t;
    eidx[tg * 2] = e1; eidx[tg * 2 + 1] = e2;
    gval[tg * 2] = p1; gval[tg * 2 + 1] = p2;
  }
}

// ---------------------------------------------------------------------------
// FCFS capacity scan: one wave per (expert, batch-row); exact cumsum semantics
// ---------------------------------------------------------------------------
__global__ void route_scan(const int* __restrict__ eidx, const float* __restrict__ gval,
                           int* __restrict__ idxl, float* __restrict__ gatel,
                           int* __restrict__ cnt)
{
  const int pair = blockIdx.x;            // e*8 + b
  const int e = pair >> 3, b = pair & 7;
  const int lane = threadIdx.x;           // blockDim = 64
  int running = 0;
  for (int t0 = 0; t0 < 2048; t0 += 64) {
    const int t = t0 + lane;
    const int i2 = (b * 2048 + t) * 2;
    const int m0 = (eidx[i2] == e), m1 = (eidx[i2 + 1] == e);
    const int m = m0 | m1;
    const float g = m0 ? gval[i2] : (m1 ? gval[i2 + 1] : 0.f);
    const unsigned long long bal = __ballot(m);
    const int pos = running + __popcll(bal & ((1ull << lane) - 1ull));
    if (m && pos < 320) { idxl[pair * 320 + pos] = t; gatel[pair * 320 + pos] = g; }
    running += __popcll(bal);
  }
  if (lane == 0) cnt[pair] = running < 320 ? running : 320;
}

// ---------------------------------------------------------------------------
// Gather kept tokens into capacity buffer [20480][1024] f16 (zeros for unused)
// ---------------------------------------------------------------------------
__global__ void gather_buf(const f16* __restrict__ xh, const int* __restrict__ cnt,
                           const int* __restrict__ idxl, f16* __restrict__ buf)
{
  const int slot = blockIdx.x;                        // 0..20479
  const int e = slot / 2560, r = slot - e * 2560;
  const int b = r / 320, s = r - b * 320;
  half8* dst = (half8*)(buf + (size_t)slot * 1024);
  if (s < cnt[e * 8 + b]) {
    const int t = idxl[(e * 8 + b) * 320 + s];
    const half8* src = (const half8*)(xh + ((size_t)b * 2048 + t) * 1024);
    dst[threadIdx.x] = src[threadIdx.x];              // 128 thr * 8 f16 = 1024
  } else {
    half8 z = {};
    dst[threadIdx.x] = z;
  }
}

// ---------------------------------------------------------------------------
extern "C" void kernel_launch(void* const* d_in, const int* in_sizes, int n_in,
                              void* d_out, int out_size, void* d_ws, size_t ws_size,
                              hipStream_t stream)
{
  (void)in_sizes; (void)n_in;
  const float* x   = (const float*)d_in[0];
  const float* rw1 = (const float*)d_in[1];
  const float* rb1 = (const float*)d_in[2];
  const float* rw2 = (const float*)d_in[3];
  const float* rb2 = (const float*)d_in[4];
  const float* rw3 = (const float*)d_in[5];
  const float* rb3 = (const float*)d_in[6];
  const float* ew1 = (const float*)d_in[7];
  const float* eb1 = (const float*)d_in[8];
  const float* ew2 = (const float*)d_in[9];
  const float* eb2 = (const float*)d_in[10];

  constexpr size_t MB = 1024ull * 1024ull;
  char* ws = (char*)d_ws;
  if (ws_size < 401 * MB) return;   // need 401 MB of scratch

  // persistent region
  f16*   ew1t  = (f16*)(ws);                         // 64MB  [E][H][C]
  f16*   ew2t  = (f16*)(ws + 64 * MB);               // 64MB  [E][C][H]
  f16*   xhi   = (f16*)(ws + 128 * MB);              // 32MB
  int*   eidx  = (int*)(ws + 160 * MB);              // 128KB
  float* gval  = (float*)(ws + 160 * MB + 128 * 1024);
  int*   idxl  = (int*)(ws + 160 * MB + 256 * 1024);
  float* gatel = (float*)(ws + 160 * MB + 384 * 1024);
  int*   cnt   = (int*)(ws + 160 * MB + 512 * 1024);
  // router-phase overlay region
  f16*   xlo    = (f16*)(ws + 161 * MB);             // 32MB
  f16*   rw1thi = (f16*)(ws + 193 * MB);             // 8MB  [H][C]
  f16*   rw1tlo = (f16*)(ws + 201 * MB);             // 8MB
  f16*   rw2thi = (f16*)(ws + 209 * MB);             // 32MB [H][H]
  f16*   rw2tlo = (f16*)(ws + 241 * MB);             // 32MB
  f16*   h1hi   = (f16*)(ws + 273 * MB);             // 32MB (4096-token chunk)
  f16*   h1lo   = (f16*)(ws + 305 * MB);             // 32MB
  float* h2     = (float*)(ws + 337 * MB);           // 64MB
  // expert-phase overlay (router buffers dead by then)
  f16*   buf    = (f16*)(ws + 161 * MB);             // 40MB  [20480][1024]
  f16*   h_e    = (f16*)(ws + 201 * MB);             // 160MB [20480][4096]

  hipMemsetAsync(d_out, 0, (size_t)out_size * sizeof(float), stream);

  // conversions / splits
  split_x<<<8192, 256, 0, stream>>>(x, xhi, xlo, 16384 * 1024);
  transpose_conv<true ><<<dim3(64, 16, 1), 256, 0, stream>>>(rw1, rw1thi, rw1tlo, 1024, 4096);
  transpose_conv<true ><<<dim3(64, 64, 1), 256, 0, stream>>>(rw2, rw2thi, rw2tlo, 4096, 4096);
  transpose_conv<false><<<dim3(64, 16, 8), 256, 0, stream>>>(ew1, ew1t, nullptr, 1024, 4096);
  transpose_conv<false><<<dim3(16, 64, 8), 256, 0, stream>>>(ew2, ew2t, nullptr, 4096, 1024);

  // router in 4 chunks of 4096 tokens (f16x3 split GEMMs = fp32-class logits)
  for (int c = 0; c < 4; ++c) {
    const f16* xh = xhi + (size_t)c * 4096 * 1024;
    const f16* xl = xlo + (size_t)c * 4096 * 1024;
    gemm128<0, true><<<dim3(32, 32), 256, 0, stream>>>(
        xh, xl, rw1thi, rw1tlo, 4096, 1024, 1024, 1024,
        rb1, 0, 0, nullptr, h1hi, h1lo, 4096, nullptr, nullptr, nullptr, nullptr);
    gemm128<1, true><<<dim3(32, 32), 256, 0, stream>>>(
        h1hi, h1lo, rw2thi, rw2tlo, 4096, 4096, 4096, 4096,
        rb2, 0, 0, h2, nullptr, nullptr, 4096, nullptr, nullptr, nullptr, nullptr);
    logits_topk<<<4096, 256, 0, stream>>>(h2, rw3, rb3, c * 4096, eidx, gval);
  }

  // dispatch
  route_scan<<<64, 64, 0, stream>>>(eidx, gval, idxl, gatel, cnt);
  gather_buf<<<20480, 128, 0, stream>>>(xhi, cnt, idxl, buf);

  // experts (plain f16; block-row -> expert weight block)
  gemm128<2, false><<<dim3(32, 160), 256, 0, stream>>>(
      buf, nullptr, ew1t, nullptr, 4096, 1024, 1024, 1024,
      eb1, 4096, 2560, nullptr, h_e, nullptr, 4096, nullptr, nullptr, nullptr, nullptr);
  gemm128<3, false><<<dim3(8, 160), 256, 0, stream>>>(
      h_e, nullptr, ew2t, nullptr, 1024, 4096, 4096, 4096,
      eb2, 1024, 2560, nullptr, nullptr, nullptr, 0, cnt, idxl, gatel, (float*)d_out);
}

// Round 2
// 2844.269 us; speedup vs baseline: 1.2981x; 1.2981x over previous
//
#include <hip/hip_runtime.h>
#include <stdint.h>

typedef _Float16 f16;
typedef _Float16 half8 __attribute__((ext_vector_type(8)));
typedef float f32x4 __attribute__((ext_vector_type(4)));

// ---------------------------------------------------------------------------
// MoE constants: B=8, T=2048, C=1024, H=4096, E=8, K=2, CAP=320
// tokens M=16384, expert slots = 20480, rows/expert = 2560
// ---------------------------------------------------------------------------

__device__ __forceinline__ void gload16(const void* g, void* l) {
  __builtin_amdgcn_global_load_lds(
      (const __attribute__((address_space(1))) void*)g,
      (__attribute__((address_space(3))) void*)l, 16, 0, 0);
}

#define BAR() do { __builtin_amdgcn_s_barrier(); __builtin_amdgcn_sched_barrier(0); } while (0)
#define WAIT_VM8() do { asm volatile("s_waitcnt vmcnt(8)" ::: "memory"); __builtin_amdgcn_sched_barrier(0); } while (0)
#define WAIT_VM0() do { asm volatile("s_waitcnt vmcnt(0)" ::: "memory"); __builtin_amdgcn_sched_barrier(0); } while (0)

// ---------------------------------------------------------------------------
// 256x256-tile f16 MFMA GEMM, 8 waves (2Mx4N), BK=64, 4-phase pipelined K-loop.
//  LDS: ring of 4 kc-half slots per operand (slot = 256 rows x 32 cols f16,
//  FRAGMENT-MAJOR: byte = mt*1024 + k8*256 + r*16  ->  ds_read addr is
//  slot + mt*1024 + lane*16 (linear, conflict-free). Staging permutation is
//  applied on the per-lane GLOBAL source address (linear LDS dest).
//  Counted vmcnt(8) twice per K-tile; raw s_barrier; setprio around MFMA.
//  A: [M][lda] f16 row-major. B stored N-major: [N][ldb] f16.
//  SPLIT3: A=A0+2^-12*A1, B=B0+2^-12*B1 (lo pre-scaled x4096); passes
//          loA*hiB, hiA*loB, (scale acc 2^-12), hiA*hiB -> fp32-class.
//  EPI: 0 relu+split-write f16(hi,lo)  1 relu+f32  2 relu+f16
//       3 +bias, gated scatter atomicAdd to out
// ---------------------------------------------------------------------------
template<int EPI, bool SPLIT3>
__launch_bounds__(512, 2)
__global__ void gemm256(const f16* __restrict__ A0, const f16* __restrict__ A1,
                        const f16* __restrict__ B0, const f16* __restrict__ B1,
                        int N, int Kd, int lda, int ldb,
                        const float* __restrict__ bias, int bias_stride, int rows_per_exp,
                        float* __restrict__ oF, f16* __restrict__ oH, f16* __restrict__ oHlo,
                        int ldo,
                        const int* __restrict__ cnt, const int* __restrict__ idxl,
                        const float* __restrict__ gatel, float* __restrict__ oScat)
{
  __shared__ f16 lds[4 * 8192 * 2 + 512];     // A ring | B ring | 1KB dummy
  f16* sA = lds;
  f16* sB = lds + 4 * 8192;
  f16* sDummy = lds + 8 * 8192;

  const int tid  = threadIdx.x;
  const int lane = tid & 63, w = tid >> 6;    // 8 waves
  const int wm = w >> 2, wn = w & 3;          // 2 x 4 wave grid

  // XCD-aware bijective swizzle (all grids are %8==0)
  const int gx  = gridDim.x;
  const int nwg = gx * gridDim.y;
  const int bid = blockIdx.y * gx + blockIdx.x;
  const int swz = (bid & 7) * (nwg >> 3) + (bid >> 3);
  const int by  = swz / gx, bx = swz - by * gx;
  const int m0  = by * 256, n0 = bx * 256;

  int e = 0;
  if (rows_per_exp > 0) e = m0 / rows_per_exp;
  const f16* Bh = B0 + (size_t)e * N * ldb;

  const int nk  = Kd >> 6;
  const int NIT = SPLIT3 ? 3 * nk : nk;

  // staging lane decode
  const int sr  = lane & 15;                  // row within 16-row m-tile
  const int sk8 = lane >> 4;                  // 16B column within 32-col half

  // stage one operand kc-half (2 x gload16/thread; wave w covers mt=w, w+8)
  auto stage = [&](const f16* base, int row0, int ld, int kk, int kc,
                   f16* slotBase, bool valid) {
    #pragma unroll
    for (int jj = 0; jj < 2; ++jj) {
      const int mt = jj * 8 + w;
      f16* dst = valid ? (slotBase + mt * 512) : sDummy;
      const f16* src = base + (size_t)(row0 + mt * 16 + sr) * ld
                            + (kk + kc * 32 + sk8 * 8);
      gload16(src, dst);
    }
  };

  struct It { const f16* Ab; const f16* Bb; int kk, kin, pass; };
  const f16* Ab0 = SPLIT3 ? A1 : A0;
  auto advance = [&](It& s) {
    if (s.kin + 1 < nk) { s.kin++; }
    else if (SPLIT3 && s.pass < 2) {
      s.kin = 0; s.pass++;
      s.Ab = (s.pass == 0) ? A1 : A0;
      s.Bb = (s.pass == 1) ? B1 : Bh;
    } // else saturate at last iteration (dest is dummy anyway)
    s.kk = s.kin << 6;
  };
  It it1 = { Ab0, Bh, 64, 1, 0 };             // j = t+1
  It it2 = { Ab0, Bh, 128, 2, 0 };            // j = t+2

  // prologue: stage (0,kc0)A/B, (0,kc1)A/B, (1,kc0)A/B -> slots 0,1,2
  stage(Ab0, m0, lda, 0, 0, &sA[0], true);
  stage(Bh,  n0, ldb, 0, 0, &sB[0], true);
  stage(Ab0, m0, lda, 0, 1, &sA[8192], true);
  stage(Bh,  n0, ldb, 0, 1, &sB[8192], true);
  stage(it1.Ab, m0, lda, it1.kk, 0, &sA[2 * 8192], true);
  stage(it1.Bb, n0, ldb, it1.kk, 0, &sB[2 * 8192], true);
  WAIT_VM8();
  BAR();

  f32x4 acc[8][4] = {};
  const int aBase = wm * 8;                   // wave's A m-tile base (8 tiles)
  const int bBase = wn * 4;                   // wave's B n-tile base (4 tiles)

  auto mfma16 = [&](half8* af, half8* bf, int moff) {
    __builtin_amdgcn_s_setprio(1);
    #pragma unroll
    for (int mi = 0; mi < 4; ++mi)
      #pragma unroll
      for (int ni = 0; ni < 4; ++ni)
        acc[moff + mi][ni] = __builtin_amdgcn_mfma_f32_16x16x32_f16(
            af[mi], bf[ni], acc[moff + mi][ni], 0, 0, 0);
    __builtin_amdgcn_s_setprio(0);
  };
  auto rdA = [&](half8* dst, int slot, int mtb) {
    #pragma unroll
    for (int mi = 0; mi < 4; ++mi)
      dst[mi] = *(const half8*)&sA[slot * 8192 + (mtb + mi) * 512 + lane * 8];
  };
  auto rdB = [&](half8* dst, int slot) {
    #pragma unroll
    for (int ni = 0; ni < 4; ++ni)
      dst[ni] = *(const half8*)&sB[slot * 8192 + (bBase + ni) * 512 + lane * 8];
  };

  for (int t = 0; t < NIT; ++t) {
    const int sa0 = (2 * t) & 3, sa1 = sa0 ^ 1;
    const bool v1 = (t + 1 < NIT), v2 = (t + 2 < NIT);

    if (SPLIT3 && t == 2 * nk) {              // lo-passes done: scale 2^-12
      #pragma unroll
      for (int mi = 0; mi < 8; ++mi)
        #pragma unroll
        for (int ni = 0; ni < 4; ++ni)
          acc[mi][ni] = acc[mi][ni] * 2.44140625e-4f;
    }

    half8 aF[4], bF[4], aG[4];

    // p0: read A(mh0,kc0)+B(kc0); stage (t+1,kc1)A -> slot sa0^3
    rdA(aF, sa0, aBase);
    rdB(bF, sa0);
    stage(it1.Ab, m0, lda, it1.kk, 1, &sA[(sa0 ^ 3) * 8192], v1);
    BAR();
    mfma16(aF, bF, 0);
    BAR();

    // p1: read A(mh1,kc0); stage (t+1,kc1)B; vmcnt(8) covers (t,kc1)
    rdA(aG, sa0, aBase + 4);
    stage(it1.Bb, n0, ldb, it1.kk, 1, &sB[(sa0 ^ 3) * 8192], v1);
    WAIT_VM8();
    BAR();
    mfma16(aG, bF, 4);
    BAR();

    // p2: read A(mh0,kc1)+B(kc1); stage (t+2,kc0)A -> slot sa0 (now dead)
    rdA(aF, sa1, aBase);
    rdB(bF, sa1);
    stage(it2.Ab, m0, lda, it2.kk, 0, &sA[sa0 * 8192], v2);
    BAR();
    mfma16(aF, bF, 0);
    BAR();

    // p3: read A(mh1,kc1); stage (t+2,kc0)B; vmcnt(8) covers (t+1,kc0)
    rdA(aG, sa1, aBase + 4);
    stage(it2.Bb, n0, ldb, it2.kk, 0, &sB[sa0 * 8192], v2);
    WAIT_VM8();
    BAR();
    mfma16(aG, bF, 4);
    BAR();

    it1 = it2;
    advance(it2);
  }
  WAIT_VM0();   // drain tail (dummy) loads before LDS is released

  // epilogue ---------------------------------------------------------------
  float bv[4];
  #pragma unroll
  for (int ni = 0; ni < 4; ++ni) {
    const int col = n0 + wn * 64 + ni * 16 + (lane & 15);
    bv[ni] = bias[(size_t)e * bias_stride + col];
  }
  #pragma unroll
  for (int mi = 0; mi < 8; ++mi) {
    #pragma unroll
    for (int r = 0; r < 4; ++r) {
      const int row = m0 + wm * 128 + mi * 16 + (lane >> 4) * 4 + r;
      if (EPI == 3) {
        const int tr = row - e * rows_per_exp;        // slot within expert
        const int bb = tr / 320, s = tr - bb * 320;   // batch row, cap slot
        const int pr = e * 8 + bb;
        if (s < cnt[pr]) {
          const int   tk = idxl[pr * 320 + s];
          const float g  = gatel[pr * 320 + s];
          float* orow = oScat + ((size_t)bb * 2048 + tk) * 1024;
          #pragma unroll
          for (int ni = 0; ni < 4; ++ni) {
            const int col = n0 + wn * 64 + ni * 16 + (lane & 15);
            atomicAdd(&orow[col], g * (acc[mi][ni][r] + bv[ni]));
          }
        }
      } else {
        #pragma unroll
        for (int ni = 0; ni < 4; ++ni) {
          const int col = n0 + wn * 64 + ni * 16 + (lane & 15);
          float v = acc[mi][ni][r] + bv[ni];
          v = fmaxf(v, 0.0f);
          const size_t o = (size_t)row * ldo + col;
          if (EPI == 0) {
            const f16 h = (f16)v;
            oH[o]   = h;
            oHlo[o] = (f16)((v - (float)h) * 4096.0f);
          } else if (EPI == 1) {
            oF[o] = v;
          } else {
            oH[o] = (f16)v;
          }
        }
      }
    }
  }
}

// ---------------------------------------------------------------------------
// x (f32) -> hi f16 + lo f16 (x4096), 8 elems/thread
// ---------------------------------------------------------------------------
__global__ void split_x(const float* __restrict__ x, f16* __restrict__ hi,
                        f16* __restrict__ lo, int n)
{
  const int i = blockIdx.x * 256 + threadIdx.x;
  if (i * 8 >= n) return;
  const f32x4 a = ((const f32x4*)x)[2 * i];
  const f32x4 b = ((const f32x4*)x)[2 * i + 1];
  half8 h, l;
  #pragma unroll
  for (int j = 0; j < 4; ++j) {
    float v = a[j]; f16 hh = (f16)v;
    h[j] = hh; l[j] = (f16)((v - (float)hh) * 4096.0f);
    v = b[j]; hh = (f16)v;
    h[4 + j] = hh; l[4 + j] = (f16)((v - (float)hh) * 4096.0f);
  }
  ((half8*)hi)[i] = h;
  ((half8*)lo)[i] = l;
}

// ---------------------------------------------------------------------------
// Transpose-convert: in f32 [R][Cc] -> out f16 [Cc][R] (optional split lo)
// ---------------------------------------------------------------------------
template<bool SPLIT>
__global__ void transpose_conv(const float* __restrict__ in, f16* __restrict__ oh,
                               f16* __restrict__ ol, int R, int Cc)
{
  __shared__ float tile[64][65];
  const size_t boff = (size_t)blockIdx.z * R * Cc;
  in += boff; oh += boff;
  if (SPLIT) ol += boff;
  const int c0 = blockIdx.x * 64, r0 = blockIdx.y * 64;
  #pragma unroll
  for (int i = 0; i < 16; ++i) {
    const int idx = i * 256 + threadIdx.x;
    const int r = idx >> 6, c = idx & 63;
    tile[r][c] = in[(size_t)(r0 + r) * Cc + (c0 + c)];
  }
  __syncthreads();
  #pragma unroll
  for (int i = 0; i < 16; ++i) {
    const int idx = i * 256 + threadIdx.x;
    const int ro = idx >> 6, co = idx & 63;
    const float v = tile[co][ro];
    const f16 h = (f16)v;
    const size_t o = (size_t)(c0 + ro) * R + (r0 + co);
    oh[o] = h;
    if (SPLIT) ol[o] = (f16)((v - (float)h) * 4096.0f);
  }
}

// ---------------------------------------------------------------------------
// logits (f64-accurate dot with rw3) + softmax f32 + stable top-2
// ---------------------------------------------------------------------------
__global__ void logits_topk(const float* __restrict__ h2, const float* __restrict__ w3,
                            const float* __restrict__ b3, int tok0,
                            int* __restrict__ eidx, float* __restrict__ gval)
{
  const int t = blockIdx.x;
  const float* hrow = h2 + (size_t)t * 4096;
  double p[8];
  #pragma unroll
  for (int e = 0; e < 8; ++e) p[e] = 0.0;
  for (int i = 0; i < 16; ++i) {
    const int k = i * 256 + threadIdx.x;
    const float h = hrow[k];
    const float* w = w3 + (size_t)k * 8;
    #pragma unroll
    for (int e = 0; e < 8; ++e) p[e] += (double)h * (double)w[e];
  }
  #pragma unroll
  for (int e = 0; e < 8; ++e)
    for (int off = 32; off > 0; off >>= 1)
      p[e] += __shfl_down(p[e], off);
  __shared__ double sp[4][8];
  const int lane = threadIdx.x & 63, wv = threadIdx.x >> 6;
  if (lane == 0) {
    #pragma unroll
    for (int e = 0; e < 8; ++e) sp[wv][e] = p[e];
  }
  __syncthreads();
  if (threadIdx.x == 0) {
    float l[8];
    #pragma unroll
    for (int e = 0; e < 8; ++e)
      l[e] = (float)(sp[0][e] + sp[1][e] + sp[2][e] + sp[3][e] + (double)b3[e]);
    float mx = l[0];
    for (int e = 1; e < 8; ++e) mx = fmaxf(mx, l[e]);
    float ex[8], s = 0.f;
    for (int e = 0; e < 8; ++e) { ex[e] = expf(l[e] - mx); s += ex[e]; }
    float p1 = -1.f, p2 = -1.f; int e1 = 0, e2 = 0;
    for (int e = 0; e < 8; ++e) {             // strict '>' = lax.top_k tie-break
      const float pe = ex[e] / s;
      if (pe > p1)      { p2 = p1; e2 = e1; p1 = pe; e1 = e; }
      else if (pe > p2) { p2 = pe; e2 = e; }
    }
    const int tg = tok0 + t;
    eidx[tg * 2] = e1; eidx[tg * 2 + 1] = e2;
    gval[tg * 2] = p1; gval[tg * 2 + 1] = p2;
  }
}

// ---------------------------------------------------------------------------
// FCFS capacity scan: one wave per (expert, batch-row); exact cumsum semantics
// ---------------------------------------------------------------------------
__global__ void route_scan(const int* __restrict__ eidx, const float* __restrict__ gval,
                           int* __restrict__ idxl, float* __restrict__ gatel,
                           int* __restrict__ cnt)
{
  const int pair = blockIdx.x;            // e*8 + b
  const int e = pair >> 3, b = pair & 7;
  const int lane = threadIdx.x;           // blockDim = 64
  int running = 0;
  for (int t0 = 0; t0 < 2048; t0 += 64) {
    const int t = t0 + lane;
    const int i2 = (b * 2048 + t) * 2;
    const int m0 = (eidx[i2] == e), m1 = (eidx[i2 + 1] == e);
    const int m = m0 | m1;
    const float g = m0 ? gval[i2] : (m1 ? gval[i2 + 1] : 0.f);
    const unsigned long long bal = __ballot(m);
    const int pos = running + __popcll(bal & ((1ull << lane) - 1ull));
    if (m && pos < 320) { idxl[pair * 320 + pos] = t; gatel[pair * 320 + pos] = g; }
    running += __popcll(bal);
  }
  if (lane == 0) cnt[pair] = running < 320 ? running : 320;
}

// ---------------------------------------------------------------------------
// Gather kept tokens into capacity buffer [20480][1024] f16 (zeros unused)
// ---------------------------------------------------------------------------
__global__ void gather_buf(const f16* __restrict__ xh, const int* __restrict__ cnt,
                           const int* __restrict__ idxl, f16* __restrict__ buf)
{
  const int slot = blockIdx.x;                        // 0..20479
  const int e = slot / 2560, r = slot - e * 2560;
  const int b = r / 320, s = r - b * 320;
  half8* dst = (half8*)(buf + (size_t)slot * 1024);
  if (s < cnt[e * 8 + b]) {
    const int t = idxl[(e * 8 + b) * 320 + s];
    const half8* src = (const half8*)(xh + ((size_t)b * 2048 + t) * 1024);
    dst[threadIdx.x] = src[threadIdx.x];              // 128 thr * 8 f16
  } else {
    half8 z = {};
    dst[threadIdx.x] = z;
  }
}

// ---------------------------------------------------------------------------
extern "C" void kernel_launch(void* const* d_in, const int* in_sizes, int n_in,
                              void* d_out, int out_size, void* d_ws, size_t ws_size,
                              hipStream_t stream)
{
  (void)in_sizes; (void)n_in;
  const float* x   = (const float*)d_in[0];
  const float* rw1 = (const float*)d_in[1];
  const float* rb1 = (const float*)d_in[2];
  const float* rw2 = (const float*)d_in[3];
  const float* rb2 = (const float*)d_in[4];
  const float* rw3 = (const float*)d_in[5];
  const float* rb3 = (const float*)d_in[6];
  const float* ew1 = (const float*)d_in[7];
  const float* eb1 = (const float*)d_in[8];
  const float* ew2 = (const float*)d_in[9];
  const float* eb2 = (const float*)d_in[10];

  constexpr size_t MB = 1024ull * 1024ull;
  char* ws = (char*)d_ws;
  if (ws_size < 401 * MB) return;   // need 401 MB of scratch

  // persistent region
  f16*   ew1t  = (f16*)(ws);                         // 64MB  [E][H][C]
  f16*   ew2t  = (f16*)(ws + 64 * MB);               // 64MB  [E][C][H]
  f16*   xhi   = (f16*)(ws + 128 * MB);              // 32MB
  int*   eidx  = (int*)(ws + 160 * MB);              // 128KB
  float* gval  = (float*)(ws + 160 * MB + 128 * 1024);
  int*   idxl  = (int*)(ws + 160 * MB + 256 * 1024);
  float* gatel = (float*)(ws + 160 * MB + 384 * 1024);
  int*   cnt   = (int*)(ws + 160 * MB + 512 * 1024);
  // router-phase overlay region
  f16*   xlo    = (f16*)(ws + 161 * MB);             // 32MB
  f16*   rw1thi = (f16*)(ws + 193 * MB);             // 8MB  [H][C]
  f16*   rw1tlo = (f16*)(ws + 201 * MB);             // 8MB
  f16*   rw2thi = (f16*)(ws + 209 * MB);             // 32MB [H][H]
  f16*   rw2tlo = (f16*)(ws + 241 * MB);             // 32MB
  f16*   h1hi   = (f16*)(ws + 273 * MB);             // 32MB (4096-token chunk)
  f16*   h1lo   = (f16*)(ws + 305 * MB);             // 32MB
  float* h2     = (float*)(ws + 337 * MB);           // 64MB
  // expert-phase overlay (router buffers dead by then)
  f16*   buf    = (f16*)(ws + 161 * MB);             // 40MB  [20480][1024]
  f16*   h_e    = (f16*)(ws + 201 * MB);             // 160MB [20480][4096]

  hipMemsetAsync(d_out, 0, (size_t)out_size * sizeof(float), stream);

  // conversions / splits
  split_x<<<8192, 256, 0, stream>>>(x, xhi, xlo, 16384 * 1024);
  transpose_conv<true ><<<dim3(64, 16, 1), 256, 0, stream>>>(rw1, rw1thi, rw1tlo, 1024, 4096);
  transpose_conv<true ><<<dim3(64, 64, 1), 256, 0, stream>>>(rw2, rw2thi, rw2tlo, 4096, 4096);
  transpose_conv<false><<<dim3(64, 16, 8), 256, 0, stream>>>(ew1, ew1t, nullptr, 1024, 4096);
  transpose_conv<false><<<dim3(16, 64, 8), 256, 0, stream>>>(ew2, ew2t, nullptr, 4096, 1024);

  // router in 4 chunks of 4096 tokens (f16x3 split GEMMs = fp32-class logits)
  for (int c = 0; c < 4; ++c) {
    const f16* xh = xhi + (size_t)c * 4096 * 1024;
    const f16* xl = xlo + (size_t)c * 4096 * 1024;
    gemm256<0, true><<<dim3(16, 16), 512, 0, stream>>>(
        xh, xl, rw1thi, rw1tlo, 4096, 1024, 1024, 1024,
        rb1, 0, 0, nullptr, h1hi, h1lo, 4096, nullptr, nullptr, nullptr, nullptr);
    gemm256<1, true><<<dim3(16, 16), 512, 0, stream>>>(
        h1hi, h1lo, rw2thi, rw2tlo, 4096, 4096, 4096, 4096,
        rb2, 0, 0, h2, nullptr, nullptr, 4096, nullptr, nullptr, nullptr, nullptr);
    logits_topk<<<4096, 256, 0, stream>>>(h2, rw3, rb3, c * 4096, eidx, gval);
  }

  // dispatch
  route_scan<<<64, 64, 0, stream>>>(eidx, gval, idxl, gatel, cnt);
  gather_buf<<<20480, 128, 0, stream>>>(xhi, cnt, idxl, buf);

  // experts (plain f16; block-row -> expert weight block)
  gemm256<2, false><<<dim3(16, 80), 512, 0, stream>>>(
      buf, nullptr, ew1t, nullptr, 4096, 1024, 1024, 1024,
      eb1, 4096, 2560, nullptr, h_e, nullptr, 4096, nullptr, nullptr, nullptr, nullptr);
  gemm256<3, false><<<dim3(4, 80), 512, 0, stream>>>(
      h_e, nullptr, ew2t, nullptr, 1024, 4096, 4096, 4096,
      eb2, 1024, 2560, nullptr, nullptr, nullptr, 0, cnt, idxl, gatel, (float*)d_out);
}

// Round 3
// 2068.332 us; speedup vs baseline: 1.7851x; 1.3752x over previous
//
#include <hip/hip_runtime.h>
#include <stdint.h>

typedef _Float16 f16;
typedef _Float16 half8 __attribute__((ext_vector_type(8)));
typedef float f32x4 __attribute__((ext_vector_type(4)));

// ---------------------------------------------------------------------------
// MoE constants: B=8, T=2048, C=1024, H=4096, E=8, K=2, CAP=320
// tokens M=16384, expert slots = 20480, rows/expert = 2560
// Router strategy: plain-f16 pipeline for all tokens; tokens with sorted
// logit gap l(2)-l(3) < THETA are recomputed through the f16x3 split pipeline
// (fp32-class) so the top-2 SET (and thus cumsum/capacity) is exact.
// ---------------------------------------------------------------------------
#define NF_MAX 2048
#define THETA  0.045f

__device__ __forceinline__ void gload16(const void* g, void* l) {
  __builtin_amdgcn_global_load_lds(
      (const __attribute__((address_space(1))) void*)g,
      (__attribute__((address_space(3))) void*)l, 16, 0, 0);
}

#define BAR() do { __builtin_amdgcn_s_barrier(); __builtin_amdgcn_sched_barrier(0); } while (0)
#define WAIT_VM8() do { asm volatile("s_waitcnt vmcnt(8)" ::: "memory"); __builtin_amdgcn_sched_barrier(0); } while (0)
#define WAIT_VM0() do { asm volatile("s_waitcnt vmcnt(0)" ::: "memory"); __builtin_amdgcn_sched_barrier(0); } while (0)

// ---------------------------------------------------------------------------
// 256x256-tile f16 MFMA GEMM, 8 waves (2Mx4N), BK=64, 4-phase pipelined K-loop
// (ring of 4 kc-half slots/operand, fragment-major LDS -> conflict-free
//  ds_read_b128; counted vmcnt(8); raw s_barrier; setprio around MFMA).
//  A: [M][lda] f16 row-major. B stored N-major: [N][ldb] f16.
//  SPLIT3: A=A0+2^-12*A1, B=B0+2^-12*B1 (lo pre-scaled x4096); passes
//          loA*hiB, hiA*loB, (scale acc 2^-12), hiA*hiB -> fp32-class.
//  EPI: 0 relu+split-write f16(hi,lo)  1 relu+f32  2 relu+f16
//       3 +bias, gated scatter atomicAdd to out
//  nfp: optional device row-count; blocks with m0 >= pad256(min(*nfp,NF_MAX))
//       exit immediately (recompute-path early exit).
// ---------------------------------------------------------------------------
template<int EPI, bool SPLIT3>
__launch_bounds__(512, 2)
__global__ void gemm256(const f16* __restrict__ A0, const f16* __restrict__ A1,
                        const f16* __restrict__ B0, const f16* __restrict__ B1,
                        int N, int Kd, int lda, int ldb,
                        const float* __restrict__ bias, int bias_stride, int rows_per_exp,
                        float* __restrict__ oF, f16* __restrict__ oH, f16* __restrict__ oHlo,
                        int ldo,
                        const int* __restrict__ cnt, const int* __restrict__ idxl,
                        const float* __restrict__ gatel, float* __restrict__ oScat,
                        const int* __restrict__ nfp)
{
  __shared__ f16 lds[4 * 8192 * 2 + 512];     // A ring | B ring | 1KB dummy
  f16* sA = lds;
  f16* sB = lds + 4 * 8192;
  f16* sDummy = lds + 8 * 8192;

  const int tid  = threadIdx.x;
  const int lane = tid & 63, w = tid >> 6;    // 8 waves
  const int wm = w >> 2, wn = w & 3;          // 2 x 4 wave grid

  // XCD-aware bijective swizzle (all grids are %8==0)
  const int gx  = gridDim.x;
  const int nwg = gx * gridDim.y;
  const int bid = blockIdx.y * gx + blockIdx.x;
  const int swz = (bid & 7) * (nwg >> 3) + (bid >> 3);
  const int by  = swz / gx, bx = swz - by * gx;
  const int m0  = by * 256, n0 = bx * 256;

  if (nfp) {                                  // recompute-path early exit
    int nf = *nfp; nf = nf < NF_MAX ? nf : NF_MAX;
    const int lim = (nf + 255) & ~255;
    if (m0 >= lim) return;
  }

  int e = 0;
  if (rows_per_exp > 0) e = m0 / rows_per_exp;
  const f16* Bh = B0 + (size_t)e * N * ldb;

  const int nk  = Kd >> 6;
  const int NIT = SPLIT3 ? 3 * nk : nk;

  // staging lane decode
  const int sr  = lane & 15;                  // row within 16-row m-tile
  const int sk8 = lane >> 4;                  // 16B column within 32-col half

  // stage one operand kc-half (2 x gload16/thread; wave w covers mt=w, w+8)
  auto stage = [&](const f16* base, int row0, int ld, int kk, int kc,
                   f16* slotBase, bool valid) {
    #pragma unroll
    for (int jj = 0; jj < 2; ++jj) {
      const int mt = jj * 8 + w;
      f16* dst = valid ? (slotBase + mt * 512) : sDummy;
      const f16* src = base + (size_t)(row0 + mt * 16 + sr) * ld
                            + (kk + kc * 32 + sk8 * 8);
      gload16(src, dst);
    }
  };

  struct It { const f16* Ab; const f16* Bb; int kk, kin, pass; };
  const f16* Ab0 = SPLIT3 ? A1 : A0;
  auto advance = [&](It& s) {
    if (s.kin + 1 < nk) { s.kin++; }
    else if (SPLIT3 && s.pass < 2) {
      s.kin = 0; s.pass++;
      s.Ab = (s.pass == 0) ? A1 : A0;
      s.Bb = (s.pass == 1) ? B1 : Bh;
    } // else saturate at last iteration (dest is dummy anyway)
    s.kk = s.kin << 6;
  };
  It it1 = { Ab0, Bh, 64, 1, 0 };             // j = t+1
  It it2 = { Ab0, Bh, 128, 2, 0 };            // j = t+2
  if (nk == 1) {                              // K=64 corner (unused but safe)
    it1.kin = 0; it1.kk = 0;
    it2.kin = 0; it2.kk = 0;
  }

  // prologue: stage (0,kc0)A/B, (0,kc1)A/B, (1,kc0)A/B -> slots 0,1,2
  stage(Ab0, m0, lda, 0, 0, &sA[0], true);
  stage(Bh,  n0, ldb, 0, 0, &sB[0], true);
  stage(Ab0, m0, lda, 0, 1, &sA[8192], true);
  stage(Bh,  n0, ldb, 0, 1, &sB[8192], true);
  stage(it1.Ab, m0, lda, it1.kk, 0, &sA[2 * 8192], true);
  stage(it1.Bb, n0, ldb, it1.kk, 0, &sB[2 * 8192], true);
  WAIT_VM8();
  BAR();

  f32x4 acc[8][4] = {};
  const int aBase = wm * 8;                   // wave's A m-tile base (8 tiles)
  const int bBase = wn * 4;                   // wave's B n-tile base (4 tiles)

  auto mfma16 = [&](half8* af, half8* bf, int moff) {
    __builtin_amdgcn_s_setprio(1);
    #pragma unroll
    for (int mi = 0; mi < 4; ++mi)
      #pragma unroll
      for (int ni = 0; ni < 4; ++ni)
        acc[moff + mi][ni] = __builtin_amdgcn_mfma_f32_16x16x32_f16(
            af[mi], bf[ni], acc[moff + mi][ni], 0, 0, 0);
    __builtin_amdgcn_s_setprio(0);
  };
  auto rdA = [&](half8* dst, int slot, int mtb) {
    #pragma unroll
    for (int mi = 0; mi < 4; ++mi)
      dst[mi] = *(const half8*)&sA[slot * 8192 + (mtb + mi) * 512 + lane * 8];
  };
  auto rdB = [&](half8* dst, int slot) {
    #pragma unroll
    for (int ni = 0; ni < 4; ++ni)
      dst[ni] = *(const half8*)&sB[slot * 8192 + (bBase + ni) * 512 + lane * 8];
  };

  for (int t = 0; t < NIT; ++t) {
    const int sa0 = (2 * t) & 3, sa1 = sa0 ^ 1;
    const bool v1 = (t + 1 < NIT), v2 = (t + 2 < NIT);

    if (SPLIT3 && t == 2 * nk) {              // lo-passes done: scale 2^-12
      #pragma unroll
      for (int mi = 0; mi < 8; ++mi)
        #pragma unroll
        for (int ni = 0; ni < 4; ++ni)
          acc[mi][ni] = acc[mi][ni] * 2.44140625e-4f;
    }

    half8 aF[4], bF[4], aG[4];

    // p0: read A(mh0,kc0)+B(kc0); stage (t+1,kc1)A -> slot sa0^3
    rdA(aF, sa0, aBase);
    rdB(bF, sa0);
    stage(it1.Ab, m0, lda, it1.kk, 1, &sA[(sa0 ^ 3) * 8192], v1);
    BAR();
    mfma16(aF, bF, 0);
    BAR();

    // p1: read A(mh1,kc0); stage (t+1,kc1)B; vmcnt(8) covers (t,kc1)
    rdA(aG, sa0, aBase + 4);
    stage(it1.Bb, n0, ldb, it1.kk, 1, &sB[(sa0 ^ 3) * 8192], v1);
    WAIT_VM8();
    BAR();
    mfma16(aG, bF, 4);
    BAR();

    // p2: read A(mh0,kc1)+B(kc1); stage (t+2,kc0)A -> slot sa0 (now dead)
    rdA(aF, sa1, aBase);
    rdB(bF, sa1);
    stage(it2.Ab, m0, lda, it2.kk, 0, &sA[sa0 * 8192], v2);
    BAR();
    mfma16(aF, bF, 0);
    BAR();

    // p3: read A(mh1,kc1); stage (t+2,kc0)B; vmcnt(8) covers (t+1,kc0)
    rdA(aG, sa1, aBase + 4);
    stage(it2.Bb, n0, ldb, it2.kk, 0, &sB[sa0 * 8192], v2);
    WAIT_VM8();
    BAR();
    mfma16(aG, bF, 4);
    BAR();

    it1 = it2;
    advance(it2);
  }
  WAIT_VM0();   // drain tail (dummy) loads before LDS is released

  // epilogue ---------------------------------------------------------------
  float bv[4];
  #pragma unroll
  for (int ni = 0; ni < 4; ++ni) {
    const int col = n0 + wn * 64 + ni * 16 + (lane & 15);
    bv[ni] = bias[(size_t)e * bias_stride + col];
  }
  #pragma unroll
  for (int mi = 0; mi < 8; ++mi) {
    #pragma unroll
    for (int r = 0; r < 4; ++r) {
      const int row = m0 + wm * 128 + mi * 16 + (lane >> 4) * 4 + r;
      if (EPI == 3) {
        const int tr = row - e * rows_per_exp;        // slot within expert
        const int bb = tr / 320, s = tr - bb * 320;   // batch row, cap slot
        const int pr = e * 8 + bb;
        if (s < cnt[pr]) {
          const int   tk = idxl[pr * 320 + s];
          const float g  = gatel[pr * 320 + s];
          float* orow = oScat + ((size_t)bb * 2048 + tk) * 1024;
          #pragma unroll
          for (int ni = 0; ni < 4; ++ni) {
            const int col = n0 + wn * 64 + ni * 16 + (lane & 15);
            atomicAdd(&orow[col], g * (acc[mi][ni][r] + bv[ni]));
          }
        }
      } else {
        #pragma unroll
        for (int ni = 0; ni < 4; ++ni) {
          const int col = n0 + wn * 64 + ni * 16 + (lane & 15);
          float v = acc[mi][ni][r] + bv[ni];
          v = fmaxf(v, 0.0f);
          const size_t o = (size_t)row * ldo + col;
          if (EPI == 0) {
            const f16 h = (f16)v;
            oH[o]   = h;
            oHlo[o] = (f16)((v - (float)h) * 4096.0f);
          } else if (EPI == 1) {
            oF[o] = v;
          } else {
            oH[o] = (f16)v;
          }
        }
      }
    }
  }
}

// ---------------------------------------------------------------------------
// x (f32) -> hi f16 + lo f16 (x4096), 8 elems/thread
// ---------------------------------------------------------------------------
__global__ void split_x(const float* __restrict__ x, f16* __restrict__ hi,
                        f16* __restrict__ lo, int n)
{
  const int i = blockIdx.x * 256 + threadIdx.x;
  if (i * 8 >= n) return;
  const f32x4 a = ((const f32x4*)x)[2 * i];
  const f32x4 b = ((const f32x4*)x)[2 * i + 1];
  half8 h, l;
  #pragma unroll
  for (int j = 0; j < 4; ++j) {
    float v = a[j]; f16 hh = (f16)v;
    h[j] = hh; l[j] = (f16)((v - (float)hh) * 4096.0f);
    v = b[j]; hh = (f16)v;
    h[4 + j] = hh; l[4 + j] = (f16)((v - (float)hh) * 4096.0f);
  }
  ((half8*)hi)[i] = h;
  ((half8*)lo)[i] = l;
}

// ---------------------------------------------------------------------------
// Transpose-convert: in f32 [R][Cc] -> out f16 [Cc][R] (optional split lo)
// ---------------------------------------------------------------------------
template<bool SPLIT>
__global__ void transpose_conv(const float* __restrict__ in, f16* __restrict__ oh,
                               f16* __restrict__ ol, int R, int Cc)
{
  __shared__ float tile[64][65];
  const size_t boff = (size_t)blockIdx.z * R * Cc;
  in += boff; oh += boff;
  if (SPLIT) ol += boff;
  const int c0 = blockIdx.x * 64, r0 = blockIdx.y * 64;
  #pragma unroll
  for (int i = 0; i < 16; ++i) {
    const int idx = i * 256 + threadIdx.x;
    const int r = idx >> 6, c = idx & 63;
    tile[r][c] = in[(size_t)(r0 + r) * Cc + (c0 + c)];
  }
  __syncthreads();
  #pragma unroll
  for (int i = 0; i < 16; ++i) {
    const int idx = i * 256 + threadIdx.x;
    const int ro = idx >> 6, co = idx & 63;
    const float v = tile[co][ro];
    const f16 h = (f16)v;
    const size_t o = (size_t)(c0 + ro) * R + (r0 + co);
    oh[o] = h;
    if (SPLIT) ol[o] = (f16)((v - (float)h) * 4096.0f);
  }
}

// ---------------------------------------------------------------------------
// FAST logits + softmax + top-2 + margin flagging. h2 is f16 (current chunk).
// Flags tokens whose sorted logit gap l(2)-l(3) < THETA for exact recompute.
// ---------------------------------------------------------------------------
__global__ void logits_topk_fast(const f16* __restrict__ h2, const float* __restrict__ w3,
                                 const float* __restrict__ b3, int tok0,
                                 int* __restrict__ eidx, float* __restrict__ gval,
                                 int* __restrict__ flags, int* __restrict__ nfc)
{
  const int t = blockIdx.x;
  const f16* hrow = h2 + (size_t)t * 4096;
  float p[8];
  #pragma unroll
  for (int e = 0; e < 8; ++e) p[e] = 0.f;
  for (int i = 0; i < 16; ++i) {
    const int k = i * 256 + threadIdx.x;
    const float h = (float)hrow[k];
    const float* w = w3 + (size_t)k * 8;
    #pragma unroll
    for (int e = 0; e < 8; ++e) p[e] = fmaf(h, w[e], p[e]);
  }
  #pragma unroll
  for (int e = 0; e < 8; ++e)
    for (int off = 32; off > 0; off >>= 1)
      p[e] += __shfl_down(p[e], off);
  __shared__ float sp[4][8];
  const int lane = threadIdx.x & 63, wv = threadIdx.x >> 6;
  if (lane == 0) {
    #pragma unroll
    for (int e = 0; e < 8; ++e) sp[wv][e] = p[e];
  }
  __syncthreads();
  if (threadIdx.x == 0) {
    float l[8];
    #pragma unroll
    for (int e = 0; e < 8; ++e)
      l[e] = sp[0][e] + sp[1][e] + sp[2][e] + sp[3][e] + b3[e];
    float mx = l[0];
    for (int e = 1; e < 8; ++e) mx = fmaxf(mx, l[e]);
    float ex[8], s = 0.f;
    for (int e = 0; e < 8; ++e) { ex[e] = expf(l[e] - mx); s += ex[e]; }
    float p1 = -1.f, p2 = -1.f; int e1 = 0, e2 = 0;
    for (int e = 0; e < 8; ++e) {             // strict '>' = lax.top_k tie-break
      const float pe = ex[e] / s;
      if (pe > p1)      { p2 = p1; e2 = e1; p1 = pe; e1 = e; }
      else if (pe > p2) { p2 = pe; e2 = e; }
    }
    const int tg = tok0 + t;
    eidx[tg * 2] = e1; eidx[tg * 2 + 1] = e2;
    gval[tg * 2] = p1; gval[tg * 2 + 1] = p2;
    // sorted-logit top-3 gap -> flag for exact recompute
    float l1 = -1e30f, l2 = -1e30f, l3 = -1e30f;
    for (int e = 0; e < 8; ++e) {
      const float le = l[e];
      if (le > l1)      { l3 = l2; l2 = l1; l1 = le; }
      else if (le > l2) { l3 = l2; l2 = le; }
      else if (le > l3) { l3 = le; }
    }
    if (l2 - l3 < THETA) {
      const int s0 = atomicAdd(nfc, 1);
      if (s0 < NF_MAX) flags[s0] = tg;
    }
  }
}

// ---------------------------------------------------------------------------
// Gather flagged tokens' x rows (hi+lo) into the recompute buffer
// ---------------------------------------------------------------------------
__global__ void flag_gather(const int* __restrict__ flags, const int* __restrict__ nfc,
                            const f16* __restrict__ xhi, const f16* __restrict__ xlo,
                            f16* __restrict__ xfh, f16* __restrict__ xfl)
{
  const int s = blockIdx.x;
  int nf = *nfc; nf = nf < NF_MAX ? nf : NF_MAX;
  if (s >= nf) return;
  const int tok = flags[s];
  const half8* sh = (const half8*)(xhi + (size_t)tok * 1024);
  const half8* sl = (const half8*)(xlo + (size_t)tok * 1024);
  half8* dh = (half8*)(xfh + (size_t)s * 1024);
  half8* dl = (half8*)(xfl + (size_t)s * 1024);
  dh[threadIdx.x] = sh[threadIdx.x];          // 128 thr * 8 f16 = 1024
  dl[threadIdx.x] = sl[threadIdx.x];
}

// ---------------------------------------------------------------------------
// EXACT logits for flagged tokens (h2r = hi + lo*2^-12, f64 accum);
// overwrites eidx/gval at the original token index.
// ---------------------------------------------------------------------------
__global__ void logits_exact(const f16* __restrict__ h2rh, const f16* __restrict__ h2rl,
                             const float* __restrict__ w3, const float* __restrict__ b3,
                             const int* __restrict__ flags, const int* __restrict__ nfc,
                             int* __restrict__ eidx, float* __restrict__ gval)
{
  const int srow = blockIdx.x;
  int nf = *nfc; nf = nf < NF_MAX ? nf : NF_MAX;
  if (srow >= nf) return;
  const f16* hh = h2rh + (size_t)srow * 4096;
  const f16* hl = h2rl + (size_t)srow * 4096;
  double p[8];
  #pragma unroll
  for (int e = 0; e < 8; ++e) p[e] = 0.0;
  for (int i = 0; i < 16; ++i) {
    const int k = i * 256 + threadIdx.x;
    const double h = (double)(float)hh[k] + (double)(float)hl[k] * 2.44140625e-4;
    const float* w = w3 + (size_t)k * 8;
    #pragma unroll
    for (int e = 0; e < 8; ++e) p[e] += h * (double)w[e];
  }
  #pragma unroll
  for (int e = 0; e < 8; ++e)
    for (int off = 32; off > 0; off >>= 1)
      p[e] += __shfl_down(p[e], off);
  __shared__ double sp[4][8];
  const int lane = threadIdx.x & 63, wv = threadIdx.x >> 6;
  if (lane == 0) {
    #pragma unroll
    for (int e = 0; e < 8; ++e) sp[wv][e] = p[e];
  }
  __syncthreads();
  if (threadIdx.x == 0) {
    float l[8];
    #pragma unroll
    for (int e = 0; e < 8; ++e)
      l[e] = (float)(sp[0][e] + sp[1][e] + sp[2][e] + sp[3][e] + (double)b3[e]);
    float mx = l[0];
    for (int e = 1; e < 8; ++e) mx = fmaxf(mx, l[e]);
    float ex[8], s = 0.f;
    for (int e = 0; e < 8; ++e) { ex[e] = expf(l[e] - mx); s += ex[e]; }
    float p1 = -1.f, p2 = -1.f; int e1 = 0, e2 = 0;
    for (int e = 0; e < 8; ++e) {
      const float pe = ex[e] / s;
      if (pe > p1)      { p2 = p1; e2 = e1; p1 = pe; e1 = e; }
      else if (pe > p2) { p2 = pe; e2 = e; }
    }
    const int tok = flags[srow];
    eidx[tok * 2] = e1; eidx[tok * 2 + 1] = e2;
    gval[tok * 2] = p1; gval[tok * 2 + 1] = p2;
  }
}

// ---------------------------------------------------------------------------
// FCFS capacity scan: one wave per (expert, batch-row); exact cumsum semantics
// ---------------------------------------------------------------------------
__global__ void route_scan(const int* __restrict__ eidx, const float* __restrict__ gval,
                           int* __restrict__ idxl, float* __restrict__ gatel,
                           int* __restrict__ cnt)
{
  const int pair = blockIdx.x;            // e*8 + b
  const int e = pair >> 3, b = pair & 7;
  const int lane = threadIdx.x;           // blockDim = 64
  int running = 0;
  for (int t0 = 0; t0 < 2048; t0 += 64) {
    const int t = t0 + lane;
    const int i2 = (b * 2048 + t) * 2;
    const int m0 = (eidx[i2] == e), m1 = (eidx[i2 + 1] == e);
    const int m = m0 | m1;
    const float g = m0 ? gval[i2] : (m1 ? gval[i2 + 1] : 0.f);
    const unsigned long long bal = __ballot(m);
    const int pos = running + __popcll(bal & ((1ull << lane) - 1ull));
    if (m && pos < 320) { idxl[pair * 320 + pos] = t; gatel[pair * 320 + pos] = g; }
    running += __popcll(bal);
  }
  if (lane == 0) cnt[pair] = running < 320 ? running : 320;
}

// ---------------------------------------------------------------------------
// Gather kept tokens into capacity buffer [20480][1024] f16 (zeros unused)
// ---------------------------------------------------------------------------
__global__ void gather_buf(const f16* __restrict__ xh, const int* __restrict__ cnt,
                           const int* __restrict__ idxl, f16* __restrict__ buf)
{
  const int slot = blockIdx.x;                        // 0..20479
  const int e = slot / 2560, r = slot - e * 2560;
  const int b = r / 320, s = r - b * 320;
  half8* dst = (half8*)(buf + (size_t)slot * 1024);
  if (s < cnt[e * 8 + b]) {
    const int t = idxl[(e * 8 + b) * 320 + s];
    const half8* src = (const half8*)(xh + ((size_t)b * 2048 + t) * 1024);
    dst[threadIdx.x] = src[threadIdx.x];              // 128 thr * 8 f16
  } else {
    half8 z = {};
    dst[threadIdx.x] = z;
  }
}

// ---------------------------------------------------------------------------
extern "C" void kernel_launch(void* const* d_in, const int* in_sizes, int n_in,
                              void* d_out, int out_size, void* d_ws, size_t ws_size,
                              hipStream_t stream)
{
  (void)in_sizes; (void)n_in;
  const float* x   = (const float*)d_in[0];
  const float* rw1 = (const float*)d_in[1];
  const float* rb1 = (const float*)d_in[2];
  const float* rw2 = (const float*)d_in[3];
  const float* rb2 = (const float*)d_in[4];
  const float* rw3 = (const float*)d_in[5];
  const float* rb3 = (const float*)d_in[6];
  const float* ew1 = (const float*)d_in[7];
  const float* eb1 = (const float*)d_in[8];
  const float* ew2 = (const float*)d_in[9];
  const float* eb2 = (const float*)d_in[10];

  constexpr size_t MB = 1024ull * 1024ull;
  char* ws = (char*)d_ws;
  if (ws_size < 401 * MB) return;   // need 401 MB of scratch

  // persistent region
  f16*   ew1t  = (f16*)(ws);                         // 64MB  [E][H][C]
  f16*   ew2t  = (f16*)(ws + 64 * MB);               // 64MB  [E][C][H]
  f16*   xhi   = (f16*)(ws + 128 * MB);              // 32MB
  int*   eidx  = (int*)(ws + 160 * MB);              // 128KB
  float* gval  = (float*)(ws + 160 * MB + 128 * 1024);
  int*   idxl  = (int*)(ws + 160 * MB + 256 * 1024); // 80KB
  float* gatel = (float*)(ws + 160 * MB + 384 * 1024);
  int*   cnt   = (int*)(ws + 160 * MB + 512 * 1024); // 256B
  int*   nfc   = (int*)(ws + 160 * MB + 516 * 1024); // 4B
  int*   flags = (int*)(ws + 160 * MB + 520 * 1024); // 8KB
  // router-phase overlay
  f16*   xlo    = (f16*)(ws + 161 * MB);             // 32MB
  f16*   rw1thi = (f16*)(ws + 193 * MB);             // 8MB  [H][C]
  f16*   rw1tlo = (f16*)(ws + 201 * MB);             // 8MB
  f16*   rw2thi = (f16*)(ws + 209 * MB);             // 32MB [H][H]
  f16*   rw2tlo = (f16*)(ws + 241 * MB);             // 32MB
  f16*   h1f    = (f16*)(ws + 273 * MB);             // 32MB  fast h1 chunk
  f16*   h2f    = (f16*)(ws + 305 * MB);             // 32MB  fast h2 chunk
  // recompute overlay (h1f/h2f dead)
  f16*   xfh  = (f16*)(ws + 273 * MB);               // 4MB  [2048][1024]
  f16*   xfl  = (f16*)(ws + 277 * MB);               // 4MB
  f16*   h1rh = (f16*)(ws + 281 * MB);               // 16MB [2048][4096]
  f16*   h1rl = (f16*)(ws + 297 * MB);               // 16MB
  f16*   h2rh = (f16*)(ws + 313 * MB);               // 16MB
  f16*   h2rl = (f16*)(ws + 329 * MB);               // 16MB -> ends 345MB
  // expert-phase overlay (router/recompute buffers dead)
  f16*   buf  = (f16*)(ws + 161 * MB);               // 40MB  [20480][1024]
  f16*   h_e  = (f16*)(ws + 201 * MB);               // 160MB [20480][4096]

  hipMemsetAsync(d_out, 0, (size_t)out_size * sizeof(float), stream);
  hipMemsetAsync(nfc, 0, sizeof(int), stream);

  // conversions / splits
  split_x<<<8192, 256, 0, stream>>>(x, xhi, xlo, 16384 * 1024);
  transpose_conv<true ><<<dim3(64, 16, 1), 256, 0, stream>>>(rw1, rw1thi, rw1tlo, 1024, 4096);
  transpose_conv<true ><<<dim3(64, 64, 1), 256, 0, stream>>>(rw2, rw2thi, rw2tlo, 4096, 4096);
  transpose_conv<false><<<dim3(64, 16, 8), 256, 0, stream>>>(ew1, ew1t, nullptr, 1024, 4096);
  transpose_conv<false><<<dim3(16, 64, 8), 256, 0, stream>>>(ew2, ew2t, nullptr, 4096, 1024);

  // FAST router: plain f16, 4 chunks of 4096 tokens
  for (int c = 0; c < 4; ++c) {
    const f16* xh = xhi + (size_t)c * 4096 * 1024;
    gemm256<2, false><<<dim3(16, 16), 512, 0, stream>>>(
        xh, nullptr, rw1thi, nullptr, 4096, 1024, 1024, 1024,
        rb1, 0, 0, nullptr, h1f, nullptr, 4096,
        nullptr, nullptr, nullptr, nullptr, nullptr);
    gemm256<2, false><<<dim3(16, 16), 512, 0, stream>>>(
        h1f, nullptr, rw2thi, nullptr, 4096, 4096, 4096, 4096,
        rb2, 0, 0, nullptr, h2f, nullptr, 4096,
        nullptr, nullptr, nullptr, nullptr, nullptr);
    logits_topk_fast<<<4096, 256, 0, stream>>>(h2f, rw3, rb3, c * 4096,
                                               eidx, gval, flags, nfc);
  }

  // EXACT recompute for flagged tokens (f16x3 split; early-exit past nf)
  hipMemsetAsync(xfh, 0, 8 * MB, stream);             // xfh+xfl contiguous
  flag_gather<<<NF_MAX, 128, 0, stream>>>(flags, nfc, xhi, xlo, xfh, xfl);
  gemm256<0, true><<<dim3(16, 8), 512, 0, stream>>>(
      xfh, xfl, rw1thi, rw1tlo, 4096, 1024, 1024, 1024,
      rb1, 0, 0, nullptr, h1rh, h1rl, 4096,
      nullptr, nullptr, nullptr, nullptr, nfc);
  gemm256<0, true><<<dim3(16, 8), 512, 0, stream>>>(
      h1rh, h1rl, rw2thi, rw2tlo, 4096, 4096, 4096, 4096,
      rb2, 0, 0, nullptr, h2rh, h2rl, 4096,
      nullptr, nullptr, nullptr, nullptr, nfc);
  logits_exact<<<NF_MAX, 256, 0, stream>>>(h2rh, h2rl, rw3, rb3, flags, nfc,
                                           eidx, gval);

  // dispatch
  route_scan<<<64, 64, 0, stream>>>(eidx, gval, idxl, gatel, cnt);
  gather_buf<<<20480, 128, 0, stream>>>(xhi, cnt, idxl, buf);

  // experts (plain f16; block-row -> expert weight block)
  gemm256<2, false><<<dim3(16, 80), 512, 0, stream>>>(
      buf, nullptr, ew1t, nullptr, 4096, 1024, 1024, 1024,
      eb1, 4096, 2560, nullptr, h_e, nullptr, 4096,
      nullptr, nullptr, nullptr, nullptr, nullptr);
  gemm256<3, false><<<dim3(4, 80), 512, 0, stream>>>(
      h_e, nullptr, ew2t, nullptr, 1024, 4096, 4096, 4096,
      eb2, 1024, 2560, nullptr, nullptr, nullptr, 0,
      cnt, idxl, gatel, (float*)d_out, nullptr);
}